// Round 5
// baseline (227.188 us; speedup 1.0000x reference)
//
#include <hip/hip_runtime.h>
#include <math.h>

#define DIM 64

static __device__ inline unsigned short f32_to_bf16(float f) {
    unsigned u = __float_as_uint(f);
    u += 0x7FFFu + ((u >> 16) & 1u);   // round-to-nearest-even
    return (unsigned short)(u >> 16);
}
static __device__ inline float bf16_to_f32(unsigned short h) {
    return __uint_as_float((unsigned)h << 16);
}

// packed csr entry: [31:15] = col (17 bits), [14:0] = coef as sign-less bf16
// (coef = sw * sigmoid * ns is always in [0,1) -> sign bit is 0, drop it)
static __device__ inline unsigned pack_entry(int c, float coef) {
    unsigned u = __float_as_uint(coef);
    u += 0x7FFFu + ((u >> 16) & 1u);           // rne to bf16
    unsigned cb = (u >> 16) & 0x7FFFu;         // drop sign
    return ((unsigned)c << 15) | cb;
}
static __device__ inline int entry_col(unsigned e) { return (int)(e >> 15); }
static __device__ inline float entry_coef(unsigned e) {
    return __uint_as_float((e & 0x7FFFu) << 16);
}

// ---------------------------------------------------------------------------
// K1: tiled dual GEMM. hxb = bf16(x @ W); self_pre = sigmoid(rep)*(x @ W_self).
// Block = 256 threads = 64-row tile; thread computes 4x4 of both outputs.
// ---------------------------------------------------------------------------
__global__ __launch_bounds__(256) void gemm_dual_tiled(
        const float* __restrict__ x,
        const float* __restrict__ W,
        const float* __restrict__ Wself,
        const float* __restrict__ rep,
        unsigned short* __restrict__ hxb,
        float* __restrict__ self_pre, int n) {
    __shared__ float xs[64][68];
    __shared__ float Ws[64][64];
    __shared__ float Vs[64][64];

    const int t = threadIdx.x;
    const int row0 = blockIdx.x * 64;

    {
        const float4* W4 = (const float4*)W;
        const float4* V4 = (const float4*)Wself;
        float4* Ws4 = (float4*)&Ws[0][0];
        float4* Vs4 = (float4*)&Vs[0][0];
        for (int i = t; i < 1024; i += 256) { Ws4[i] = W4[i]; Vs4[i] = V4[i]; }
    }
    for (int i = t; i < 1024; i += 256) {
        int r = i >> 4, c4 = i & 15;
        float4 v = make_float4(0.f, 0.f, 0.f, 0.f);
        if (row0 + r < n) v = ((const float4*)x)[(size_t)(row0 + r) * 16 + c4];
        *(float4*)&xs[r][c4 * 4] = v;
    }
    __syncthreads();

    const int r0 = (t >> 4) * 4;
    const int c0 = (t & 15) * 4;

    float4 a1[4], a2[4];
#pragma unroll
    for (int j = 0; j < 4; ++j) {
        a1[j] = make_float4(0.f, 0.f, 0.f, 0.f);
        a2[j] = make_float4(0.f, 0.f, 0.f, 0.f);
    }

#pragma unroll 8
    for (int k = 0; k < 64; ++k) {
        float4 wv = *(const float4*)&Ws[k][c0];
        float4 vv = *(const float4*)&Vs[k][c0];
        float xk0 = xs[r0 + 0][k];
        float xk1 = xs[r0 + 1][k];
        float xk2 = xs[r0 + 2][k];
        float xk3 = xs[r0 + 3][k];

        a1[0].x = fmaf(xk0, wv.x, a1[0].x); a1[0].y = fmaf(xk0, wv.y, a1[0].y);
        a1[0].z = fmaf(xk0, wv.z, a1[0].z); a1[0].w = fmaf(xk0, wv.w, a1[0].w);
        a1[1].x = fmaf(xk1, wv.x, a1[1].x); a1[1].y = fmaf(xk1, wv.y, a1[1].y);
        a1[1].z = fmaf(xk1, wv.z, a1[1].z); a1[1].w = fmaf(xk1, wv.w, a1[1].w);
        a1[2].x = fmaf(xk2, wv.x, a1[2].x); a1[2].y = fmaf(xk2, wv.y, a1[2].y);
        a1[2].z = fmaf(xk2, wv.z, a1[2].z); a1[2].w = fmaf(xk2, wv.w, a1[2].w);
        a1[3].x = fmaf(xk3, wv.x, a1[3].x); a1[3].y = fmaf(xk3, wv.y, a1[3].y);
        a1[3].z = fmaf(xk3, wv.z, a1[3].z); a1[3].w = fmaf(xk3, wv.w, a1[3].w);

        a2[0].x = fmaf(xk0, vv.x, a2[0].x); a2[0].y = fmaf(xk0, vv.y, a2[0].y);
        a2[0].z = fmaf(xk0, vv.z, a2[0].z); a2[0].w = fmaf(xk0, vv.w, a2[0].w);
        a2[1].x = fmaf(xk1, vv.x, a2[1].x); a2[1].y = fmaf(xk1, vv.y, a2[1].y);
        a2[1].z = fmaf(xk1, vv.z, a2[1].z); a2[1].w = fmaf(xk1, vv.w, a2[1].w);
        a2[2].x = fmaf(xk2, vv.x, a2[2].x); a2[2].y = fmaf(xk2, vv.y, a2[2].y);
        a2[2].z = fmaf(xk2, vv.z, a2[2].z); a2[2].w = fmaf(xk2, vv.w, a2[2].w);
        a2[3].x = fmaf(xk3, vv.x, a2[3].x); a2[3].y = fmaf(xk3, vv.y, a2[3].y);
        a2[3].z = fmaf(xk3, vv.z, a2[3].z); a2[3].w = fmaf(xk3, vv.w, a2[3].w);
    }

#pragma unroll
    for (int j = 0; j < 4; ++j) {
        int row = row0 + r0 + j;
        if (row >= n) break;
        ushort4 hb;
        hb.x = f32_to_bf16(a1[j].x); hb.y = f32_to_bf16(a1[j].y);
        hb.z = f32_to_bf16(a1[j].z); hb.w = f32_to_bf16(a1[j].w);
        *(ushort4*)&hxb[(size_t)row * DIM + c0] = hb;
        float srep = 1.0f / (1.0f + __expf(-rep[row]));
        float4 sp = make_float4(srep * a2[j].x, srep * a2[j].y,
                                srep * a2[j].z, srep * a2[j].w);
        *(float4*)&self_pre[(size_t)row * DIM + c0] = sp;
    }
}

// ---------------------------------------------------------------------------
// CSR build: histogram -> scan -> fill (coef fused into fill, 4B entries).
// ---------------------------------------------------------------------------
__global__ void hist_kernel(const int* __restrict__ ei, int* __restrict__ cnt, int E) {
    int e = blockIdx.x * blockDim.x + threadIdx.x;
    if (e < E) atomicAdd(&cnt[ei[e]], 1);
}

__global__ void scan_tile_kernel(const int* __restrict__ cnt,
                                 int* __restrict__ row_ptr,
                                 int* __restrict__ blk_sums, int n) {
    __shared__ int wsum[16];
    const int tid = threadIdx.x;
    const int lane = tid & 63;
    const int wv = tid >> 6;
    int i = blockIdx.x * 1024 + tid;
    int v = (i < n) ? cnt[i] : 0;
    int s = v;
#pragma unroll
    for (int off = 1; off < 64; off <<= 1) {
        int t = __shfl_up(s, off, 64);
        if (lane >= off) s += t;
    }
    if (lane == 63) wsum[wv] = s;
    __syncthreads();
    if (wv == 0 && lane < 16) {
        int w = wsum[lane], sw = w;
#pragma unroll
        for (int off = 1; off < 16; off <<= 1) {
            int t = __shfl_up(sw, off, 16);
            if (lane >= off) sw += t;
        }
        wsum[lane] = sw - w;
    }
    __syncthreads();
    int excl = wsum[wv] + (s - v);
    if (i < n) row_ptr[i] = excl;
    if (tid == 1023) blk_sums[blockIdx.x] = wsum[15] + s;
}

__global__ void scan_blk_kernel(int* __restrict__ blk_sums, int nb) {
    __shared__ int sh[256];
    const int tid = threadIdx.x;
    sh[tid] = (tid < nb) ? blk_sums[tid] : 0;
    __syncthreads();
    for (int off = 1; off < 256; off <<= 1) {
        int t = 0;
        if (tid >= off) t = sh[tid - off];
        __syncthreads();
        if (tid >= off) sh[tid] += t;
        __syncthreads();
    }
    if (tid < nb) blk_sums[tid] = (tid == 0) ? 0 : sh[tid - 1];
}

__global__ void scan_add_kernel(int* __restrict__ row_ptr,
                                const int* __restrict__ blk_sums,
                                int* __restrict__ cursor, int n, int E) {
    int i = blockIdx.x * 1024 + threadIdx.x;
    if (i < n) {
        int v = row_ptr[i] + blk_sums[blockIdx.x];
        row_ptr[i] = v;
        cursor[i]  = v;
    }
    if (blockIdx.x == 0 && threadIdx.x == 0) row_ptr[n] = E;
}

__global__ void fill_kernel(const int* __restrict__ ei,
                            const float* __restrict__ sw,
                            const float* __restrict__ rep,
                            const float* __restrict__ ns,
                            int* __restrict__ cursor,
                            unsigned* __restrict__ csr, int E) {
    int e = blockIdx.x * blockDim.x + threadIdx.x;
    if (e >= E) return;
    int r = ei[e];
    int c = ei[E + e];
    float gate = 1.0f / (1.0f + __expf(-(rep[r] + rep[c])));
    float coef = sw[e] * gate * ns[c];
    int slot = atomicAdd(&cursor[r], 1);
    csr[slot] = pack_entry(c, coef);
}

// ---------------------------------------------------------------------------
// K-final: pure gather + FMA + epilogue. One wave per row; packed entries for
// 64 edges fetched with one coalesced lane load; ONE shfl per edge; 8
// independent bf16 hx gathers in flight per chunk.
// ---------------------------------------------------------------------------
template<int K>
__device__ inline void gather_k(int j, unsigned pk,
                                const unsigned short* __restrict__ hxb,
                                int lane, float& acc) {
    int c[K]; float w[K]; unsigned short h[K];
#pragma unroll
    for (int i = 0; i < K; ++i) {
        unsigned ep = (unsigned)__shfl((int)pk, j + i, 64);
        c[i] = entry_col(ep);
        w[i] = entry_coef(ep);
    }
#pragma unroll
    for (int i = 0; i < K; ++i) h[i] = hxb[(size_t)c[i] * DIM + lane];
#pragma unroll
    for (int i = 0; i < K; ++i) acc = fmaf(w[i], bf16_to_f32(h[i]), acc);
}

__global__ void gather_finalize_kernel(const int* __restrict__ row_ptr,
                                       const unsigned* __restrict__ csr,
                                       const unsigned short* __restrict__ hxb,
                                       const float* __restrict__ self_pre,
                                       float* __restrict__ out, int n) {
    const int lane = threadIdx.x & 63;
    const int wave = threadIdx.x >> 6;
    const int wpb  = blockDim.x >> 6;

    for (int row = blockIdx.x * wpb + wave; row < n; row += gridDim.x * wpb) {
        const int beg = row_ptr[row];
        const int end = row_ptr[row + 1];
        float acc = 0.0f;

        for (int base = beg; base < end; base += 64) {
            int m = end - base;
            if (m > 64) m = 64;
            unsigned pk = csr[base + (lane < m ? lane : 0)];

            int j = 0;
            for (; j + 8 <= m; j += 8) gather_k<8>(j, pk, hxb, lane, acc);
            if (j + 4 <= m) { gather_k<4>(j, pk, hxb, lane, acc); j += 4; }
            if (j + 2 <= m) { gather_k<2>(j, pk, hxb, lane, acc); j += 2; }
            if (j < m)      { gather_k<1>(j, pk, hxb, lane, acc); }
        }

        float deg = (float)(end - beg);
        float v = acc / (deg + 1e-6f) + self_pre[(size_t)row * DIM + lane];
        out[(size_t)row * DIM + lane] = (v > 0.0f) ? v : 0.01f * v;
    }
}

// ---------------------------------------------------------------------------
// Fallback (small ws): atomic-scatter path (f32 hx).
// ---------------------------------------------------------------------------
__global__ void gemm64_kernel(const float* __restrict__ x,
                              const float* __restrict__ W,
                              float* __restrict__ hx, int n) {
    __shared__ float Ws[DIM * DIM];
    for (int i = threadIdx.x; i < DIM * DIM; i += blockDim.x) Ws[i] = W[i];
    __syncthreads();
    const int lane = threadIdx.x & 63;
    const int wave = threadIdx.x >> 6;
    const int wpb  = blockDim.x >> 6;
    for (int row = blockIdx.x * wpb + wave; row < n; row += gridDim.x * wpb) {
        float xv = x[(size_t)row * DIM + lane];
        float acc = 0.0f;
#pragma unroll
        for (int k = 0; k < 64; ++k)
            acc = fmaf(__shfl(xv, k, 64), Ws[k * DIM + lane], acc);
        hx[(size_t)row * DIM + lane] = acc;
    }
}

__global__ void edge_scatter_kernel(const int* __restrict__ ei,
                                    const float* __restrict__ sw,
                                    const float* __restrict__ rep,
                                    const float* __restrict__ ns,
                                    const float* __restrict__ hx,
                                    float* __restrict__ out,
                                    float* __restrict__ deg, int E) {
    long long t = (long long)blockIdx.x * blockDim.x + threadIdx.x;
    int e = (int)(t >> 6);
    int d = (int)(t & 63);
    if (e >= E) return;
    int r = ei[e];
    int c = ei[E + e];
    float gate = 1.0f / (1.0f + __expf(-(rep[r] + rep[c])));
    float coef = sw[e] * gate * ns[c];
    atomicAdd(&out[(size_t)r * DIM + d], coef * hx[(size_t)c * DIM + d]);
    if (d == 0) atomicAdd(&deg[r], 1.0f);
}

__global__ void finalize_kernel(const float* __restrict__ x,
                                const float* __restrict__ Wself,
                                const float* __restrict__ rep,
                                const float* __restrict__ deg,
                                float* __restrict__ out, int n) {
    __shared__ float Ws[DIM * DIM];
    for (int i = threadIdx.x; i < DIM * DIM; i += blockDim.x) Ws[i] = Wself[i];
    __syncthreads();
    const int lane = threadIdx.x & 63;
    const int wave = threadIdx.x >> 6;
    const int wpb  = blockDim.x >> 6;
    for (int row = blockIdx.x * wpb + wave; row < n; row += gridDim.x * wpb) {
        float xv = x[(size_t)row * DIM + lane];
        float self = 0.0f;
#pragma unroll
        for (int k = 0; k < 64; ++k)
            self = fmaf(__shfl(xv, k, 64), Ws[k * DIM + lane], self);
        float srep = 1.0f / (1.0f + __expf(-rep[row]));
        float v = out[(size_t)row * DIM + lane] / (deg[row] + 1e-6f) + srep * self;
        out[(size_t)row * DIM + lane] = (v > 0.0f) ? v : 0.01f * v;
    }
}

// ---------------------------------------------------------------------------
extern "C" void kernel_launch(void* const* d_in, const int* in_sizes, int n_in,
                              void* d_out, int out_size, void* d_ws, size_t ws_size,
                              hipStream_t stream) {
    const float* x     = (const float*)d_in[0];
    const int*   ei    = (const int*)d_in[1];
    const float* sw    = (const float*)d_in[2];
    const float* rep   = (const float*)d_in[3];
    const float* ns    = (const float*)d_in[4];
    const float* W     = (const float*)d_in[5];
    const float* Wself = (const float*)d_in[6];

    const int n = in_sizes[0] / DIM;   // 100000
    const int E = in_sizes[2];         // 1600000

    float* out = (float*)d_out;
    char*  ws  = (char*)d_ws;

    size_t off = 0;
    unsigned short* hxb = (unsigned short*)(ws + off); off += (size_t)n * DIM * 2;  // 12.8 MB
    float*    self_pre = (float*)(ws + off);  off += (size_t)n * DIM * 4;           // 25.6 MB
    unsigned* csr      = (unsigned*)(ws + off); off += (size_t)E * 4;               // 6.4 MB
    int*      cnt      = (int*)(ws + off);    off += (size_t)n * 4;
    int*      row_ptr  = (int*)(ws + off);    off += (size_t)(n + 1) * 4;
    int*      cursor   = (int*)(ws + off);    off += (size_t)n * 4;
    int*      blk_sums = (int*)(ws + off);    off += 256 * 4;
    const size_t need = off;

    const int nb = (n + 1023) / 1024;

    if (ws_size >= need && nb <= 256) {
        hipMemsetAsync(cnt, 0, (size_t)n * sizeof(int), stream);

        gemm_dual_tiled<<<(n + 63) / 64, 256, 0, stream>>>(
            x, W, Wself, rep, hxb, self_pre, n);

        hist_kernel<<<(E + 255) / 256, 256, 0, stream>>>(ei, cnt, E);
        scan_tile_kernel<<<nb, 1024, 0, stream>>>(cnt, row_ptr, blk_sums, n);
        scan_blk_kernel<<<1, 256, 0, stream>>>(blk_sums, nb);
        scan_add_kernel<<<nb, 1024, 0, stream>>>(row_ptr, blk_sums, cursor, n, E);
        fill_kernel<<<(E + 255) / 256, 256, 0, stream>>>(ei, sw, rep, ns, cursor, csr, E);
        {
            const int block = 256, wpb = block / 64;
            gather_finalize_kernel<<<(n + wpb - 1) / wpb, block, 0, stream>>>(
                row_ptr, csr, hxb, self_pre, out, n);
        }
    } else {
        float* hx2 = (float*)ws;
        float* deg = (float*)ws + (size_t)n * DIM;
        hipMemsetAsync(d_out, 0, (size_t)out_size * sizeof(float), stream);
        hipMemsetAsync(deg, 0, (size_t)n * sizeof(float), stream);
        {
            const int block = 256, wpb = block / 64;
            gemm64_kernel<<<(n + wpb - 1) / wpb, block, 0, stream>>>(x, W, hx2, n);
        }
        {
            long long total = (long long)E * DIM;
            edge_scatter_kernel<<<(int)((total + 255) / 256), 256, 0, stream>>>(
                ei, sw, rep, ns, hx2, out, deg, E);
        }
        {
            const int block = 256, wpb = block / 64;
            finalize_kernel<<<(n + wpb - 1) / wpb, block, 0, stream>>>(
                x, Wself, rep, deg, out, n);
        }
    }
}